// Round 4
// baseline (539.305 us; speedup 1.0000x reference)
//
#include <hip/hip_runtime.h>
#include <hip/hip_bf16.h>

typedef _Float16 half8 __attribute__((ext_vector_type(8)));
typedef float floatx16 __attribute__((ext_vector_type(16)));

// ---------------------------------------------------------------------------
// Swizzled LDS layouts (chunk = 8 halfs = 16B, rotated by row).
// act buffers: 64x256 fp16 (32 KiB). x buffer: 64x64 fp16 (8 KiB).
// ---------------------------------------------------------------------------
__device__ __forceinline__ int swz(int row, int col) {
    return row * 256 + ((((col >> 3) + row) & 31) << 3) + (col & 7);
}
__device__ __forceinline__ int xswz(int row, int col) {
    return row * 64 + ((((col >> 3) + row) & 7) << 3) + (col & 7);
}

// ---------------------------------------------------------------------------
// Weight pre-pack: fp32 (K,N) row-major -> fp16 B-fragment order for
// v_mfma_f32_32x32x16_f16: tile = 16k x 32n; lane L holds
// B[kt*16 + 8*(L>>5) + j][nt*32 + (L&31)], j=0..7.
// K zero-padded to EVEN k-step counts: L1 39->64 (KT=4), L5 295->320 (KT=20),
// others 256 (KT=16). L9 N 4->32. Tile starts (in 1KB tiles):
// {0,32,160,288,416,576,704,832,960}, total 976 tiles = 999424 B in d_ws.
// ---------------------------------------------------------------------------
__global__ void pack_w32(const float* __restrict__ w1, const float* __restrict__ w2,
                         const float* __restrict__ w3, const float* __restrict__ w4,
                         const float* __restrict__ w5, const float* __restrict__ w6,
                         const float* __restrict__ w7, const float* __restrict__ w8,
                         const float* __restrict__ w9, _Float16* __restrict__ dst) {
    const int tileStart[10] = {0, 32, 160, 288, 416, 576, 704, 832, 960, 976};
    const int Ks[9] = {39, 256, 256, 256, 295, 256, 256, 256, 256};
    const int Ns[9] = {256, 256, 256, 256, 256, 256, 256, 256, 4};
    const int Tn[9] = {8, 8, 8, 8, 8, 8, 8, 8, 1};
    const float* ws[9] = {w1, w2, w3, w4, w5, w6, w7, w8, w9};

    int g = blockIdx.x * blockDim.x + threadIdx.x;
    int tile = g >> 6, lane = g & 63;
    if (tile >= 976) return;
    int layer = 0;
    while (tile >= tileStart[layer + 1]) layer++;
    int t = tile - tileStart[layer];
    int tn = Tn[layer];
    int kt = t / tn, nt = t - kt * tn;
    int k0 = kt * 16 + (lane >> 5) * 8;
    int n = nt * 32 + (lane & 31);
    const float* w = ws[layer];
    int K = Ks[layer], N = Ns[layer];
    _Float16 v[8];
#pragma unroll
    for (int j = 0; j < 8; j++) {
        int k = k0 + j;
        v[j] = (k < K && n < N) ? (_Float16)w[k * N + n] : (_Float16)0.f;
    }
    *(half8*)(dst + (size_t)tile * 512 + lane * 8) = *(half8*)v;
}

// A-fragment read for k-step ks (rows 0..31 -> a0, 32..63 -> a1).
// AMODE 0: act buffer. 1: ks>=KS0 from x buffer (layer-5 skip concat).
// 2: entirely from x buffer (layer 1).
template <int AMODE, int KS0>
__device__ __forceinline__ void loadA(const _Float16* __restrict__ abuf,
                                      const _Float16* __restrict__ xbuf,
                                      int ks, int l31, int lhi,
                                      half8& a0, half8& a1) {
    if (AMODE == 2 || (AMODE == 1 && ks >= KS0)) {
        int c = ((AMODE == 2) ? ks : (ks - KS0)) * 16 + lhi * 8;
        a0 = *(const half8*)(xbuf + xswz(l31, c));
        a1 = *(const half8*)(xbuf + xswz(32 + l31, c));
    } else {
        int c = ks * 16 + lhi * 8;
        a0 = *(const half8*)(abuf + swz(l31, c));
        a1 = *(const half8*)(abuf + swz(32 + l31, c));
    }
}

// ---------------------------------------------------------------------------
// One fused layer: C(64x256) = relu(A(64xK) @ W + b), LDS->LDS.
// R4: 8 waves per block; wave owns a 32-col slice (1 n-tile), 2 m-tiles.
// Small per-wave live set (2 accs, 2+2 B-frags, 4+4 A-frags) fits the
// 128-VGPR cap of __launch_bounds__(512,4) -> 4 waves/SIMD of TLP.
// A-frag ds_reads are pipelined one full iteration (2 k-steps) ahead,
// matching the depth-2 global B prefetch ring -> fine-grained waitcnts.
// ---------------------------------------------------------------------------
template <int KT, int AMODE, int KS0>
__device__ __forceinline__ void layerf32(const _Float16* __restrict__ abuf,
                                         const _Float16* __restrict__ xbuf,
                                         const half8* __restrict__ wq,
                                         const float* __restrict__ bias,
                                         _Float16* __restrict__ obuf,
                                         int lane, int wave) {
    static_assert((KT & 1) == 0 && KT >= 4, "KT must be even >= 4");
    const int l31 = lane & 31, lhi = lane >> 5;
    // b-frag for (kstep ks, ntile=wave): wq[(ks*8 + wave)*64 + lane] = wl[ks*512]
    const half8* wl = wq + wave * 64 + lane;
    float bv = bias[wave * 32 + l31];
    floatx16 acc0 = {}, acc1 = {};
    half8 bA = wl[0];
    half8 bB = wl[512];
    half8 aA0, aA1, aB0, aB1;
    loadA<AMODE, KS0>(abuf, xbuf, 0, l31, lhi, aA0, aA1);
    loadA<AMODE, KS0>(abuf, xbuf, 1, l31, lhi, aB0, aB1);
#pragma unroll 1
    for (int ks = 0; ks < KT - 2; ks += 2) {
        half8 nA = wl[(ks + 2) * 512];
        half8 nB = wl[(ks + 3) * 512];
        half8 pA0, pA1, pB0, pB1;
        loadA<AMODE, KS0>(abuf, xbuf, ks + 2, l31, lhi, pA0, pA1);
        loadA<AMODE, KS0>(abuf, xbuf, ks + 3, l31, lhi, pB0, pB1);
        acc0 = __builtin_amdgcn_mfma_f32_32x32x16_f16(aA0, bA, acc0, 0, 0, 0);
        acc1 = __builtin_amdgcn_mfma_f32_32x32x16_f16(aA1, bA, acc1, 0, 0, 0);
        acc0 = __builtin_amdgcn_mfma_f32_32x32x16_f16(aB0, bB, acc0, 0, 0, 0);
        acc1 = __builtin_amdgcn_mfma_f32_32x32x16_f16(aB1, bB, acc1, 0, 0, 0);
        aA0 = pA0; aA1 = pA1; aB0 = pB0; aB1 = pB1;
        bA = nA; bB = nB;
    }
    acc0 = __builtin_amdgcn_mfma_f32_32x32x16_f16(aA0, bA, acc0, 0, 0, 0);
    acc1 = __builtin_amdgcn_mfma_f32_32x32x16_f16(aA1, bA, acc1, 0, 0, 0);
    acc0 = __builtin_amdgcn_mfma_f32_32x32x16_f16(aB0, bB, acc0, 0, 0, 0);
    acc1 = __builtin_amdgcn_mfma_f32_32x32x16_f16(aB1, bB, acc1, 0, 0, 0);
    // Epilogue: bias + relu + fp16. C layout: col=lane&31,
    // row=(r&3)+8*(r>>2)+4*(lane>>5).
    const int col = wave * 32 + l31;
#pragma unroll
    for (int m = 0; m < 2; m++) {
#pragma unroll
        for (int r = 0; r < 16; r++) {
            int row = m * 32 + lhi * 4 + (r & 3) + ((r >> 2) << 3);
            float v = (m ? acc1[r] : acc0[r]) + bv;
            v = v > 0.f ? v : 0.f;
            obuf[swz(row, col)] = (_Float16)v;
        }
    }
}

// Layer 9: 256 -> 4 (N padded to 32). Waves 0,1 take one 32-row m-tile each.
__device__ __forceinline__ void layer9f(const _Float16* __restrict__ abuf,
                                        const half8* __restrict__ wq,
                                        const float* __restrict__ b9,
                                        float* __restrict__ out, long r0,
                                        int lane, int wave) {
    if (wave >= 2) return;
    const int l31 = lane & 31, lhi = lane >> 5;
    floatx16 acc = {};
    half8 bc = wq[lane];
#pragma unroll 1
    for (int ks = 0; ks < 15; ks++) {
        half8 bn = wq[(ks + 1) * 64 + lane];
        half8 a = *(const half8*)(abuf + swz(wave * 32 + l31, ks * 16 + lhi * 8));
        acc = __builtin_amdgcn_mfma_f32_32x32x16_f16(a, bc, acc, 0, 0, 0);
        bc = bn;
    }
    half8 a = *(const half8*)(abuf + swz(wave * 32 + l31, 15 * 16 + lhi * 8));
    acc = __builtin_amdgcn_mfma_f32_32x32x16_f16(a, bc, acc, 0, 0, 0);
    if (l31 < 4) {
        float bv = b9[l31];
#pragma unroll
        for (int r = 0; r < 16; r++) {
            int row = wave * 32 + lhi * 4 + (r & 3) + ((r >> 2) << 3);
            out[(r0 + row) * 4 + l31] = acc[r] + bv;
        }
    }
}

__global__ __launch_bounds__(512, 4) void mlp_fused(
    const float* __restrict__ x, const _Float16* __restrict__ wpk,
    const float* __restrict__ b1, const float* __restrict__ b2,
    const float* __restrict__ b3, const float* __restrict__ b4,
    const float* __restrict__ b5, const float* __restrict__ b6,
    const float* __restrict__ b7, const float* __restrict__ b8,
    const float* __restrict__ b9, float* __restrict__ out) {
    // 2 x 32 KiB activation ping-pong + 8 KiB persistent x tile = 72 KiB
    // -> 2 blocks/CU; 8 waves/block -> 16 waves/CU = 4 waves/SIMD (vs 2 in R3).
    __shared__ _Float16 lds[2 * 64 * 256 + 64 * 64];
    _Float16* buf0 = lds;
    _Float16* buf1 = lds + 64 * 256;
    _Float16* xbuf = lds + 2 * 64 * 256;
    const int tid = threadIdx.x;
    const int lane = tid & 63, wave = tid >> 6;
    const long r0 = (long)blockIdx.x * 64;

    // Stage x: zero pad cols (39..63) and fill cols 0..38 — disjoint, one barrier.
    for (int i = tid; i < 64 * 25; i += 512) {
        int row = i / 25, col = 39 + (i - row * 25);
        xbuf[xswz(row, col)] = (_Float16)0.f;
    }
    for (int i = tid; i < 64 * 39; i += 512) {
        int row = i / 39, col = i - row * 39;
        xbuf[xswz(row, col)] = (_Float16)x[r0 * 39 + i];  // contiguous 2496 floats
    }
    __syncthreads();

    const half8* wp = (const half8*)wpk;  // tile = 64 half8
    const half8* w1q = wp + (size_t)0 * 64;
    const half8* w2q = wp + (size_t)32 * 64;
    const half8* w3q = wp + (size_t)160 * 64;
    const half8* w4q = wp + (size_t)288 * 64;
    const half8* w5q = wp + (size_t)416 * 64;
    const half8* w6q = wp + (size_t)576 * 64;
    const half8* w7q = wp + (size_t)704 * 64;
    const half8* w8q = wp + (size_t)832 * 64;
    const half8* w9q = wp + (size_t)960 * 64;

    layerf32<4, 2, 0>(xbuf, xbuf, w1q, b1, buf1, lane, wave);
    __syncthreads();
    layerf32<16, 0, 0>(buf1, xbuf, w2q, b2, buf0, lane, wave);
    __syncthreads();
    layerf32<16, 0, 0>(buf0, xbuf, w3q, b3, buf1, lane, wave);
    __syncthreads();
    layerf32<16, 0, 0>(buf1, xbuf, w4q, b4, buf0, lane, wave);
    __syncthreads();
    layerf32<20, 1, 16>(buf0, xbuf, w5q, b5, buf1, lane, wave);  // [h|x] skip
    __syncthreads();
    layerf32<16, 0, 0>(buf1, xbuf, w6q, b6, buf0, lane, wave);
    __syncthreads();
    layerf32<16, 0, 0>(buf0, xbuf, w7q, b7, buf1, lane, wave);
    __syncthreads();
    layerf32<16, 0, 0>(buf1, xbuf, w8q, b8, buf0, lane, wave);
    __syncthreads();
    layer9f(buf0, w9q, b9, out, r0, lane, wave);
}

extern "C" void kernel_launch(void* const* d_in, const int* in_sizes, int n_in,
                              void* d_out, int out_size, void* d_ws, size_t ws_size,
                              hipStream_t stream) {
    const float* x = (const float*)d_in[0];
    const float* w[9];
    const float* b[9];
    for (int i = 0; i < 9; i++) {
        w[i] = (const float*)d_in[1 + 2 * i];
        b[i] = (const float*)d_in[2 + 2 * i];
    }
    _Float16* wpk = (_Float16*)d_ws;  // 999424 B

    pack_w32<<<244, 256, 0, stream>>>(w[0], w[1], w[2], w[3], w[4], w[5], w[6], w[7], w[8], wpk);
    mlp_fused<<<262144 / 64, 512, 0, stream>>>(x, wpk, b[0], b[1], b[2], b[3], b[4],
                                               b[5], b[6], b[7], b[8], (float*)d_out);
}

// Round 5
// 403.749 us; speedup vs baseline: 1.3357x; 1.3357x over previous
//
#include <hip/hip_runtime.h>
#include <hip/hip_bf16.h>

typedef _Float16 half8 __attribute__((ext_vector_type(8)));
typedef float floatx16 __attribute__((ext_vector_type(16)));

// ---------------------------------------------------------------------------
// Swizzled LDS layouts (chunk = 8 halfs = 16B, rotated by row).
// act buffer: 64x256 fp16 (32 KiB, SINGLE buffer, read->barrier->write in
// place). x buffer: 64x64 fp16 (8 KiB). Total 40 KiB -> exactly 4 blocks/CU.
// ---------------------------------------------------------------------------
__device__ __forceinline__ int swz(int row, int col) {
    return row * 256 + ((((col >> 3) + row) & 31) << 3) + (col & 7);
}
__device__ __forceinline__ int xswz(int row, int col) {
    return row * 64 + ((((col >> 3) + row) & 7) << 3) + (col & 7);
}

// ---------------------------------------------------------------------------
// Weight pre-pack: fp32 (K,N) row-major -> fp16 B-fragment order for
// v_mfma_f32_32x32x16_f16: tile = 16k x 32n; lane L holds
// B[kt*16 + 8*(L>>5) + j][nt*32 + (L&31)], j=0..7.
// K zero-padded to EVEN k-step counts: L1 39->64 (KT=4), L5 295->320 (KT=20),
// others 256 (KT=16). L9 N 4->32. Tile starts (in 1KB tiles):
// {0,32,160,288,416,576,704,832,960}, total 976 tiles = 999424 B in d_ws.
// ---------------------------------------------------------------------------
__global__ void pack_w32(const float* __restrict__ w1, const float* __restrict__ w2,
                         const float* __restrict__ w3, const float* __restrict__ w4,
                         const float* __restrict__ w5, const float* __restrict__ w6,
                         const float* __restrict__ w7, const float* __restrict__ w8,
                         const float* __restrict__ w9, _Float16* __restrict__ dst) {
    const int tileStart[10] = {0, 32, 160, 288, 416, 576, 704, 832, 960, 976};
    const int Ks[9] = {39, 256, 256, 256, 295, 256, 256, 256, 256};
    const int Ns[9] = {256, 256, 256, 256, 256, 256, 256, 256, 4};
    const int Tn[9] = {8, 8, 8, 8, 8, 8, 8, 8, 1};
    const float* ws[9] = {w1, w2, w3, w4, w5, w6, w7, w8, w9};

    int g = blockIdx.x * blockDim.x + threadIdx.x;
    int tile = g >> 6, lane = g & 63;
    if (tile >= 976) return;
    int layer = 0;
    while (tile >= tileStart[layer + 1]) layer++;
    int t = tile - tileStart[layer];
    int tn = Tn[layer];
    int kt = t / tn, nt = t - kt * tn;
    int k0 = kt * 16 + (lane >> 5) * 8;
    int n = nt * 32 + (lane & 31);
    const float* w = ws[layer];
    int K = Ks[layer], N = Ns[layer];
    _Float16 v[8];
#pragma unroll
    for (int j = 0; j < 8; j++) {
        int k = k0 + j;
        v[j] = (k < K && n < N) ? (_Float16)w[k * N + n] : (_Float16)0.f;
    }
    *(half8*)(dst + (size_t)tile * 512 + lane * 8) = *(half8*)v;
}

// A-fragment read for k-step ks (rows 0..31 -> a0, 32..63 -> a1).
// AMODE 0: act buffer. 1: ks>=KS0 from x buffer (layer-5 skip concat).
// 2: entirely from x buffer (layer 1).
template <int AMODE, int KS0>
__device__ __forceinline__ void loadA(const _Float16* abuf,
                                      const _Float16* __restrict__ xbuf,
                                      int ks, int l31, int lhi,
                                      half8& a0, half8& a1) {
    if (AMODE == 2 || (AMODE == 1 && ks >= KS0)) {
        int c = ((AMODE == 2) ? ks : (ks - KS0)) * 16 + lhi * 8;
        a0 = *(const half8*)(xbuf + xswz(l31, c));
        a1 = *(const half8*)(xbuf + xswz(32 + l31, c));
    } else {
        int c = ks * 16 + lhi * 8;
        a0 = *(const half8*)(abuf + swz(l31, c));
        a1 = *(const half8*)(abuf + swz(32 + l31, c));
    }
}

// ---------------------------------------------------------------------------
// One fused layer: C(64x256) = relu(A(64xK) @ W + b), in-place LDS->LDS.
// 4 waves; wave owns 64 cols (2 n-tiles of 32), 2 m-tiles of 32 rows.
// R3's proven loop body (fits 128 VGPR incl. AGPRs => 4 waves/SIMD possible):
// real k-loop (#pragma unroll 1), depth-2 global B prefetch ring, A-frags
// read in-iteration from LDS. NEW in R5: single act buffer — a barrier
// between the k-loop (reads) and the epilogue (writes) makes in-place safe,
// cutting LDS to 40 KiB so 4 blocks/CU co-reside (vs 2 in R3).
// ---------------------------------------------------------------------------
template <int KT, int AMODE, int KS0>
__device__ __forceinline__ void layerf32(const _Float16* abuf,
                                         const _Float16* __restrict__ xbuf,
                                         const half8* __restrict__ wq,
                                         const float* __restrict__ bias,
                                         _Float16* obuf,
                                         int lane, int wave) {
    static_assert((KT & 1) == 0 && KT >= 4, "KT must be even >= 4");
    const int l31 = lane & 31, lhi = lane >> 5;
    // b-frag for (kstep ks, n-tile n): wq[(ks*8 + wave*2 + n)*64 + lane]
    const half8* wl = wq + (wave * 2) * 64 + lane;
    float bv0 = bias[wave * 64 + l31];
    float bv1 = bias[wave * 64 + 32 + l31];
    floatx16 acc00 = {}, acc01 = {}, acc10 = {}, acc11 = {};
    half8 bA0 = wl[0], bA1 = wl[64];
    half8 bB0 = wl[512], bB1 = wl[512 + 64];
#pragma unroll 1
    for (int ks = 0; ks < KT - 2; ks += 2) {
        half8 nA0 = wl[(ks + 2) * 512], nA1 = wl[(ks + 2) * 512 + 64];
        half8 nB0 = wl[(ks + 3) * 512], nB1 = wl[(ks + 3) * 512 + 64];
        half8 a0, a1;
        loadA<AMODE, KS0>(abuf, xbuf, ks, l31, lhi, a0, a1);
        acc00 = __builtin_amdgcn_mfma_f32_32x32x16_f16(a0, bA0, acc00, 0, 0, 0);
        acc01 = __builtin_amdgcn_mfma_f32_32x32x16_f16(a0, bA1, acc01, 0, 0, 0);
        acc10 = __builtin_amdgcn_mfma_f32_32x32x16_f16(a1, bA0, acc10, 0, 0, 0);
        acc11 = __builtin_amdgcn_mfma_f32_32x32x16_f16(a1, bA1, acc11, 0, 0, 0);
        loadA<AMODE, KS0>(abuf, xbuf, ks + 1, l31, lhi, a0, a1);
        acc00 = __builtin_amdgcn_mfma_f32_32x32x16_f16(a0, bB0, acc00, 0, 0, 0);
        acc01 = __builtin_amdgcn_mfma_f32_32x32x16_f16(a0, bB1, acc01, 0, 0, 0);
        acc10 = __builtin_amdgcn_mfma_f32_32x32x16_f16(a1, bB0, acc10, 0, 0, 0);
        acc11 = __builtin_amdgcn_mfma_f32_32x32x16_f16(a1, bB1, acc11, 0, 0, 0);
        bA0 = nA0; bA1 = nA1; bB0 = nB0; bB1 = nB1;
    }
    {   // tail: k-steps KT-2 (bA) and KT-1 (bB), no prefetch
        half8 a0, a1;
        loadA<AMODE, KS0>(abuf, xbuf, KT - 2, l31, lhi, a0, a1);
        acc00 = __builtin_amdgcn_mfma_f32_32x32x16_f16(a0, bA0, acc00, 0, 0, 0);
        acc01 = __builtin_amdgcn_mfma_f32_32x32x16_f16(a0, bA1, acc01, 0, 0, 0);
        acc10 = __builtin_amdgcn_mfma_f32_32x32x16_f16(a1, bA0, acc10, 0, 0, 0);
        acc11 = __builtin_amdgcn_mfma_f32_32x32x16_f16(a1, bA1, acc11, 0, 0, 0);
        loadA<AMODE, KS0>(abuf, xbuf, KT - 1, l31, lhi, a0, a1);
        acc00 = __builtin_amdgcn_mfma_f32_32x32x16_f16(a0, bB0, acc00, 0, 0, 0);
        acc01 = __builtin_amdgcn_mfma_f32_32x32x16_f16(a0, bB1, acc01, 0, 0, 0);
        acc10 = __builtin_amdgcn_mfma_f32_32x32x16_f16(a1, bB0, acc10, 0, 0, 0);
        acc11 = __builtin_amdgcn_mfma_f32_32x32x16_f16(a1, bB1, acc11, 0, 0, 0);
    }
    // In-place safety barrier: all waves' A-reads complete before any C-write.
    // Layer 1 (AMODE 2) reads only xbuf, so no barrier needed there.
    if (AMODE != 2) __syncthreads();
    // Epilogue: bias + relu + fp16. C layout: col=lane&31,
    // row=(r&3)+8*(r>>2)+4*(lane>>5).
    floatx16 accs[2][2] = {{acc00, acc01}, {acc10, acc11}};
#pragma unroll
    for (int n = 0; n < 2; n++) {
        float bv = n ? bv1 : bv0;
        int col = wave * 64 + n * 32 + l31;
#pragma unroll
        for (int m = 0; m < 2; m++) {
#pragma unroll
            for (int r = 0; r < 16; r++) {
                int row = m * 32 + lhi * 4 + (r & 3) + ((r >> 2) << 3);
                float v = accs[m][n][r] + bv;
                v = v > 0.f ? v : 0.f;
                obuf[swz(row, col)] = (_Float16)v;
            }
        }
    }
}

// Layer 9: 256 -> 4 (N padded to 32). Waves 0,1 take one 32-row m-tile each.
__device__ __forceinline__ void layer9f(const _Float16* abuf,
                                        const half8* __restrict__ wq,
                                        const float* __restrict__ b9,
                                        float* __restrict__ out, long r0,
                                        int lane, int wave) {
    if (wave >= 2) return;
    const int l31 = lane & 31, lhi = lane >> 5;
    floatx16 acc = {};
    half8 bc = wq[lane];
#pragma unroll 1
    for (int ks = 0; ks < 15; ks++) {
        half8 bn = wq[(ks + 1) * 64 + lane];
        half8 a = *(const half8*)(abuf + swz(wave * 32 + l31, ks * 16 + lhi * 8));
        acc = __builtin_amdgcn_mfma_f32_32x32x16_f16(a, bc, acc, 0, 0, 0);
        bc = bn;
    }
    half8 a = *(const half8*)(abuf + swz(wave * 32 + l31, 15 * 16 + lhi * 8));
    acc = __builtin_amdgcn_mfma_f32_32x32x16_f16(a, bc, acc, 0, 0, 0);
    if (l31 < 4) {
        float bv = b9[l31];
#pragma unroll
        for (int r = 0; r < 16; r++) {
            int row = wave * 32 + lhi * 4 + (r & 3) + ((r >> 2) << 3);
            out[(r0 + row) * 4 + l31] = acc[r] + bv;
        }
    }
}

__global__ __launch_bounds__(256, 2) void mlp_fused(
    const float* __restrict__ x, const _Float16* __restrict__ wpk,
    const float* __restrict__ b1, const float* __restrict__ b2,
    const float* __restrict__ b3, const float* __restrict__ b4,
    const float* __restrict__ b5, const float* __restrict__ b6,
    const float* __restrict__ b7, const float* __restrict__ b8,
    const float* __restrict__ b9, float* __restrict__ out) {
    // Single 32 KiB act buffer + 8 KiB x tile = 40960 B -> exactly 4 blocks/CU
    // (4 x 40960 = 160 KiB). 16 waves/CU = 4 waves/SIMD at 128 VGPR/wave.
    __shared__ _Float16 lds[64 * 256 + 64 * 64];
    _Float16* buf = lds;
    _Float16* xbuf = lds + 64 * 256;
    const int tid = threadIdx.x;
    const int lane = tid & 63, wave = tid >> 6;
    const long r0 = (long)blockIdx.x * 64;

    // Stage x: zero pad cols (39..63) and fill cols 0..38 — disjoint, one barrier.
    for (int i = tid; i < 64 * 25; i += 256) {
        int row = i / 25, col = 39 + (i - row * 25);
        xbuf[xswz(row, col)] = (_Float16)0.f;
    }
    for (int i = tid; i < 64 * 39; i += 256) {
        int row = i / 39, col = i - row * 39;
        xbuf[xswz(row, col)] = (_Float16)x[r0 * 39 + i];  // contiguous 2496 floats
    }
    __syncthreads();

    const half8* wp = (const half8*)wpk;  // tile = 64 half8
    const half8* w1q = wp + (size_t)0 * 64;
    const half8* w2q = wp + (size_t)32 * 64;
    const half8* w3q = wp + (size_t)160 * 64;
    const half8* w4q = wp + (size_t)288 * 64;
    const half8* w5q = wp + (size_t)416 * 64;
    const half8* w6q = wp + (size_t)576 * 64;
    const half8* w7q = wp + (size_t)704 * 64;
    const half8* w8q = wp + (size_t)832 * 64;
    const half8* w9q = wp + (size_t)960 * 64;

    layerf32<4, 2, 0>(xbuf, xbuf, w1q, b1, buf, lane, wave);   // x -> buf
    __syncthreads();
    layerf32<16, 0, 0>(buf, xbuf, w2q, b2, buf, lane, wave);
    __syncthreads();
    layerf32<16, 0, 0>(buf, xbuf, w3q, b3, buf, lane, wave);
    __syncthreads();
    layerf32<16, 0, 0>(buf, xbuf, w4q, b4, buf, lane, wave);
    __syncthreads();
    layerf32<20, 1, 16>(buf, xbuf, w5q, b5, buf, lane, wave);  // [h|x] skip
    __syncthreads();
    layerf32<16, 0, 0>(buf, xbuf, w6q, b6, buf, lane, wave);
    __syncthreads();
    layerf32<16, 0, 0>(buf, xbuf, w7q, b7, buf, lane, wave);
    __syncthreads();
    layerf32<16, 0, 0>(buf, xbuf, w8q, b8, buf, lane, wave);
    __syncthreads();
    layer9f(buf, w9q, b9, out, r0, lane, wave);
}

extern "C" void kernel_launch(void* const* d_in, const int* in_sizes, int n_in,
                              void* d_out, int out_size, void* d_ws, size_t ws_size,
                              hipStream_t stream) {
    const float* x = (const float*)d_in[0];
    const float* w[9];
    const float* b[9];
    for (int i = 0; i < 9; i++) {
        w[i] = (const float*)d_in[1 + 2 * i];
        b[i] = (const float*)d_in[2 + 2 * i];
    }
    _Float16* wpk = (_Float16*)d_ws;  // 999424 B

    pack_w32<<<244, 256, 0, stream>>>(w[0], w[1], w[2], w[3], w[4], w[5], w[6], w[7], w[8], wpk);
    mlp_fused<<<262144 / 64, 256, 0, stream>>>(x, wpk, b[0], b[1], b[2], b[3], b[4],
                                               b[5], b[6], b[7], b[8], (float*)d_out);
}

// Round 6
// 399.275 us; speedup vs baseline: 1.3507x; 1.0112x over previous
//
#include <hip/hip_runtime.h>
#include <hip/hip_bf16.h>

typedef _Float16 half8 __attribute__((ext_vector_type(8)));
typedef float floatx16 __attribute__((ext_vector_type(16)));

// ---------------------------------------------------------------------------
// Swizzled LDS layouts (chunk = 8 halfs = 16B, rotated by row).
// act buffer: 64x256 fp16 (32 KiB, single, in-place read->barrier->write).
// x buffer: 64x64 fp16 (8 KiB). Total 40960 B.
// ---------------------------------------------------------------------------
__device__ __forceinline__ int swz(int row, int col) {
    return row * 256 + ((((col >> 3) + row) & 31) << 3) + (col & 7);
}
__device__ __forceinline__ int xswz(int row, int col) {
    return row * 64 + ((((col >> 3) + row) & 7) << 3) + (col & 7);
}

// ---------------------------------------------------------------------------
// Weight pre-pack: fp32 (K,N) row-major -> fp16 B-fragment order for
// v_mfma_f32_32x32x16_f16: tile = 16k x 32n; lane L holds
// B[kt*16 + 8*(L>>5) + j][nt*32 + (L&31)], j=0..7.
// K zero-padded to EVEN k-step counts: L1 39->64 (KT=4), L5 295->320 (KT=20),
// others 256 (KT=16). L9 N 4->32. Tile starts (in 1KB tiles):
// {0,32,160,288,416,576,704,832,960}, total 976 tiles = 999424 B in d_ws.
// ---------------------------------------------------------------------------
__global__ void pack_w32(const float* __restrict__ w1, const float* __restrict__ w2,
                         const float* __restrict__ w3, const float* __restrict__ w4,
                         const float* __restrict__ w5, const float* __restrict__ w6,
                         const float* __restrict__ w7, const float* __restrict__ w8,
                         const float* __restrict__ w9, _Float16* __restrict__ dst) {
    const int tileStart[10] = {0, 32, 160, 288, 416, 576, 704, 832, 960, 976};
    const int Ks[9] = {39, 256, 256, 256, 295, 256, 256, 256, 256};
    const int Ns[9] = {256, 256, 256, 256, 256, 256, 256, 256, 4};
    const int Tn[9] = {8, 8, 8, 8, 8, 8, 8, 8, 1};
    const float* ws[9] = {w1, w2, w3, w4, w5, w6, w7, w8, w9};

    int g = blockIdx.x * blockDim.x + threadIdx.x;
    int tile = g >> 6, lane = g & 63;
    if (tile >= 976) return;
    int layer = 0;
    while (tile >= tileStart[layer + 1]) layer++;
    int t = tile - tileStart[layer];
    int tn = Tn[layer];
    int kt = t / tn, nt = t - kt * tn;
    int k0 = kt * 16 + (lane >> 5) * 8;
    int n = nt * 32 + (lane & 31);
    const float* w = ws[layer];
    int K = Ks[layer], N = Ns[layer];
    _Float16 v[8];
#pragma unroll
    for (int j = 0; j < 8; j++) {
        int k = k0 + j;
        v[j] = (k < K && n < N) ? (_Float16)w[k * N + n] : (_Float16)0.f;
    }
    *(half8*)(dst + (size_t)tile * 512 + lane * 8) = *(half8*)v;
}

// A-fragment read for k-step ks (rows 0..31 -> a0, 32..63 -> a1).
// AMODE 0: act buffer. 1: ks>=KS0 from x buffer (layer-5 skip concat).
// 2: entirely from x buffer (layer 1).
template <int AMODE, int KS0>
__device__ __forceinline__ void loadA(const _Float16* abuf,
                                      const _Float16* __restrict__ xbuf,
                                      int ks, int l31, int lhi,
                                      half8& a0, half8& a1) {
    if (AMODE == 2 || (AMODE == 1 && ks >= KS0)) {
        int c = ((AMODE == 2) ? ks : (ks - KS0)) * 16 + lhi * 8;
        a0 = *(const half8*)(xbuf + xswz(l31, c));
        a1 = *(const half8*)(xbuf + xswz(32 + l31, c));
    } else {
        int c = ks * 16 + lhi * 8;
        a0 = *(const half8*)(abuf + swz(l31, c));
        a1 = *(const half8*)(abuf + swz(32 + l31, c));
    }
}

// ---------------------------------------------------------------------------
// One fused layer: C(64x256) = relu(A(64xK) @ W + b), in-place LDS->LDS.
// R6: 8 waves; wave owns ONE 32-col n-tile (exclusive -> L2 B-traffic
// unchanged) x 2 m-tiles. Lean per-wave live set: 2 accs (32 acc regs) +
// depth-2 B ring (32 arch) + in-iteration A-frags (16 arch) + addressing
// ~= 66 arch — fits __launch_bounds__(512,4)'s 128-total cap WITHOUT the
// A-register-pipeline that spilled R4. Target: 2 blocks/CU x 8 waves =
// 4 waves/SIMD (vs 2 in R3/R5), no scratch.
// ---------------------------------------------------------------------------
template <int KT, int AMODE, int KS0>
__device__ __forceinline__ void layerf32(const _Float16* abuf,
                                         const _Float16* __restrict__ xbuf,
                                         const half8* __restrict__ wq,
                                         const float* __restrict__ bias,
                                         _Float16* obuf,
                                         int lane, int wave) {
    static_assert((KT & 1) == 0 && KT >= 4, "KT must be even >= 4");
    const int l31 = lane & 31, lhi = lane >> 5;
    // b-frag for (kstep ks, n-tile wave): wq[(ks*8 + wave)*64 + lane] = wl[ks*512]
    const half8* wl = wq + wave * 64 + lane;
    float bv = bias[wave * 32 + l31];
    floatx16 acc0 = {}, acc1 = {};
    half8 bA = wl[0];
    half8 bB = wl[512];
#pragma unroll 1
    for (int ks = 0; ks < KT - 2; ks += 2) {
        half8 nA = wl[(ks + 2) * 512];
        half8 nB = wl[(ks + 3) * 512];
        half8 a0, a1;
        loadA<AMODE, KS0>(abuf, xbuf, ks, l31, lhi, a0, a1);
        acc0 = __builtin_amdgcn_mfma_f32_32x32x16_f16(a0, bA, acc0, 0, 0, 0);
        acc1 = __builtin_amdgcn_mfma_f32_32x32x16_f16(a1, bA, acc1, 0, 0, 0);
        loadA<AMODE, KS0>(abuf, xbuf, ks + 1, l31, lhi, a0, a1);
        acc0 = __builtin_amdgcn_mfma_f32_32x32x16_f16(a0, bB, acc0, 0, 0, 0);
        acc1 = __builtin_amdgcn_mfma_f32_32x32x16_f16(a1, bB, acc1, 0, 0, 0);
        bA = nA; bB = nB;
    }
    {   // tail: k-steps KT-2 (bA) and KT-1 (bB), no prefetch
        half8 a0, a1;
        loadA<AMODE, KS0>(abuf, xbuf, KT - 2, l31, lhi, a0, a1);
        acc0 = __builtin_amdgcn_mfma_f32_32x32x16_f16(a0, bA, acc0, 0, 0, 0);
        acc1 = __builtin_amdgcn_mfma_f32_32x32x16_f16(a1, bA, acc1, 0, 0, 0);
        loadA<AMODE, KS0>(abuf, xbuf, KT - 1, l31, lhi, a0, a1);
        acc0 = __builtin_amdgcn_mfma_f32_32x32x16_f16(a0, bB, acc0, 0, 0, 0);
        acc1 = __builtin_amdgcn_mfma_f32_32x32x16_f16(a1, bB, acc1, 0, 0, 0);
    }
    // In-place safety barrier: all waves' A-reads complete before any C-write.
    // Layer 1 (AMODE 2) reads only xbuf -> no barrier needed.
    if (AMODE != 2) __syncthreads();
    // Epilogue: bias + relu + fp16. C layout: col=lane&31,
    // row=(r&3)+8*(r>>2)+4*(lane>>5).
    const int col = wave * 32 + l31;
#pragma unroll
    for (int m = 0; m < 2; m++) {
#pragma unroll
        for (int r = 0; r < 16; r++) {
            int row = m * 32 + lhi * 4 + (r & 3) + ((r >> 2) << 3);
            float v = (m ? acc1[r] : acc0[r]) + bv;
            v = v > 0.f ? v : 0.f;
            obuf[swz(row, col)] = (_Float16)v;
        }
    }
}

// Layer 9: 256 -> 4 (N padded to 32). Waves 0,1 take one 32-row m-tile each.
__device__ __forceinline__ void layer9f(const _Float16* abuf,
                                        const half8* __restrict__ wq,
                                        const float* __restrict__ b9,
                                        float* __restrict__ out, long r0,
                                        int lane, int wave) {
    if (wave >= 2) return;
    const int l31 = lane & 31, lhi = lane >> 5;
    floatx16 acc = {};
    half8 bc = wq[lane];
#pragma unroll 1
    for (int ks = 0; ks < 15; ks++) {
        half8 bn = wq[(ks + 1) * 64 + lane];
        half8 a = *(const half8*)(abuf + swz(wave * 32 + l31, ks * 16 + lhi * 8));
        acc = __builtin_amdgcn_mfma_f32_32x32x16_f16(a, bc, acc, 0, 0, 0);
        bc = bn;
    }
    half8 a = *(const half8*)(abuf + swz(wave * 32 + l31, 15 * 16 + lhi * 8));
    acc = __builtin_amdgcn_mfma_f32_32x32x16_f16(a, bc, acc, 0, 0, 0);
    if (l31 < 4) {
        float bv = b9[l31];
#pragma unroll
        for (int r = 0; r < 16; r++) {
            int row = wave * 32 + lhi * 4 + (r & 3) + ((r >> 2) << 3);
            out[(r0 + row) * 4 + l31] = acc[r] + bv;
        }
    }
}

__global__ __launch_bounds__(512, 4) void mlp_fused(
    const float* __restrict__ x, const _Float16* __restrict__ wpk,
    const float* __restrict__ b1, const float* __restrict__ b2,
    const float* __restrict__ b3, const float* __restrict__ b4,
    const float* __restrict__ b5, const float* __restrict__ b6,
    const float* __restrict__ b7, const float* __restrict__ b8,
    const float* __restrict__ b9, float* __restrict__ out) {
    // Single 32 KiB act buffer + 8 KiB x tile = 40960 B. 8-wave blocks;
    // 2 blocks/CU = 16 waves/CU = 4 waves/SIMD at <=128 total regs/wave.
    __shared__ _Float16 lds[64 * 256 + 64 * 64];
    _Float16* buf = lds;
    _Float16* xbuf = lds + 64 * 256;
    const int tid = threadIdx.x;
    const int lane = tid & 63, wave = tid >> 6;
    const long r0 = (long)blockIdx.x * 64;

    // Stage x: zero pad cols (39..63) and fill cols 0..38 — disjoint, one barrier.
    for (int i = tid; i < 64 * 25; i += 512) {
        int row = i / 25, col = 39 + (i - row * 25);
        xbuf[xswz(row, col)] = (_Float16)0.f;
    }
    for (int i = tid; i < 64 * 39; i += 512) {
        int row = i / 39, col = i - row * 39;
        xbuf[xswz(row, col)] = (_Float16)x[r0 * 39 + i];  // contiguous 2496 floats
    }
    __syncthreads();

    const half8* wp = (const half8*)wpk;  // tile = 64 half8
    const half8* w1q = wp + (size_t)0 * 64;
    const half8* w2q = wp + (size_t)32 * 64;
    const half8* w3q = wp + (size_t)160 * 64;
    const half8* w4q = wp + (size_t)288 * 64;
    const half8* w5q = wp + (size_t)416 * 64;
    const half8* w6q = wp + (size_t)576 * 64;
    const half8* w7q = wp + (size_t)704 * 64;
    const half8* w8q = wp + (size_t)832 * 64;
    const half8* w9q = wp + (size_t)960 * 64;

    layerf32<4, 2, 0>(xbuf, xbuf, w1q, b1, buf, lane, wave);   // x -> buf
    __syncthreads();
    layerf32<16, 0, 0>(buf, xbuf, w2q, b2, buf, lane, wave);
    __syncthreads();
    layerf32<16, 0, 0>(buf, xbuf, w3q, b3, buf, lane, wave);
    __syncthreads();
    layerf32<16, 0, 0>(buf, xbuf, w4q, b4, buf, lane, wave);
    __syncthreads();
    layerf32<20, 1, 16>(buf, xbuf, w5q, b5, buf, lane, wave);  // [h|x] skip
    __syncthreads();
    layerf32<16, 0, 0>(buf, xbuf, w6q, b6, buf, lane, wave);
    __syncthreads();
    layerf32<16, 0, 0>(buf, xbuf, w7q, b7, buf, lane, wave);
    __syncthreads();
    layerf32<16, 0, 0>(buf, xbuf, w8q, b8, buf, lane, wave);
    __syncthreads();
    layer9f(buf, w9q, b9, out, r0, lane, wave);
}

extern "C" void kernel_launch(void* const* d_in, const int* in_sizes, int n_in,
                              void* d_out, int out_size, void* d_ws, size_t ws_size,
                              hipStream_t stream) {
    const float* x = (const float*)d_in[0];
    const float* w[9];
    const float* b[9];
    for (int i = 0; i < 9; i++) {
        w[i] = (const float*)d_in[1 + 2 * i];
        b[i] = (const float*)d_in[2 + 2 * i];
    }
    _Float16* wpk = (_Float16*)d_ws;  // 999424 B

    pack_w32<<<244, 256, 0, stream>>>(w[0], w[1], w[2], w[3], w[4], w[5], w[6], w[7], w[8], wpk);
    mlp_fused<<<262144 / 64, 512, 0, stream>>>(x, wpk, b[0], b[1], b[2], b[3], b[4],
                                               b[5], b[6], b[7], b[8], (float*)d_out);
}